// Round 15
// baseline (360.623 us; speedup 1.0000x reference)
//
#include <hip/hip_runtime.h>
#include <hip/hip_bf16.h>
#include <math.h>

// Problem constants
#define B   64
#define C   1024
#define HH  16
#define DD  64
#define MM  2048
#define LL  2049   // M+1
#define SCALE 0.125f
#define NCHC 9     // ctx row chunks
#define CHC  228   // rows per ctx chunk (9*228 = 2052 >= 2049)

typedef __attribute__((ext_vector_type(8))) short short8v;   // 8 bf16
typedef __attribute__((ext_vector_type(4))) short short4v;   // 4 bf16
typedef __attribute__((ext_vector_type(4))) float f32x4;

__device__ __forceinline__ short f2bf(float x) {
  unsigned u = __float_as_uint(x);
  unsigned r = u + 0x7FFFu + ((u >> 16) & 1u);
  return (short)(r >> 16);
}
__device__ __forceinline__ float bf2f(short b) {
  return __uint_as_float(((unsigned)(unsigned short)b) << 16);
}

// ---------------- generic split-K GEMM: out_partial[kc][64][1024] ----------------
__global__ __launch_bounds__(256) void k_gemm(
    const float* __restrict__ A, int a_row_stride, int a_bx_off,
    const float* __restrict__ W, float* __restrict__ P) {
  __shared__ __attribute__((aligned(16))) float a_s[64 * 132];
  __shared__ __attribute__((aligned(16))) float b_s[128 * 68];
  int t = threadIdx.x;
  int jt = blockIdx.x, kc = blockIdx.y;
  const float* Ab = A + (size_t)jt * a_bx_off;
  int k0 = kc * 128;
  for (int idx = t; idx < 2048; idx += 256) {
    int bb = idx >> 5, f4 = idx & 31;
    float4 v = *(const float4*)&Ab[(size_t)bb * a_row_stride + k0 + 4 * f4];
    *(float4*)&a_s[bb * 132 + 4 * f4] = v;
  }
  for (int idx = t; idx < 2048; idx += 256) {
    int kk = idx >> 4, f4 = idx & 15;
    float4 v = *(const float4*)&W[(size_t)(k0 + kk) * 1024 + jt * 64 + 4 * f4];
    *(float4*)&b_s[kk * 68 + 4 * f4] = v;
  }
  __syncthreads();
  int j0 = (t & 15) * 4, b0 = (t >> 4) * 4;
  float4 acc[4];
#pragma unroll
  for (int i = 0; i < 4; ++i) acc[i] = make_float4(0.f, 0.f, 0.f, 0.f);
  for (int k = 0; k < 128; k += 4) {
    float4 w0 = *(const float4*)&b_s[(k + 0) * 68 + j0];
    float4 w1 = *(const float4*)&b_s[(k + 1) * 68 + j0];
    float4 w2 = *(const float4*)&b_s[(k + 2) * 68 + j0];
    float4 w3 = *(const float4*)&b_s[(k + 3) * 68 + j0];
#pragma unroll
    for (int i = 0; i < 4; ++i) {
      float4 av = *(const float4*)&a_s[(b0 + i) * 132 + k];
      acc[i].x += av.x * w0.x + av.y * w1.x + av.z * w2.x + av.w * w3.x;
      acc[i].y += av.x * w0.y + av.y * w1.y + av.z * w2.y + av.w * w3.y;
      acc[i].z += av.x * w0.z + av.y * w1.z + av.z * w2.z + av.w * w3.z;
      acc[i].w += av.x * w0.w + av.y * w1.w + av.z * w2.w + av.w * w3.w;
    }
  }
  size_t ob = (size_t)kc * 65536 + jt * 64;
#pragma unroll
  for (int i = 0; i < 4; ++i)
    *(float4*)&P[ob + (size_t)(b0 + i) * 1024 + j0] = acc[i];
}

__global__ __launch_bounds__(256) void k_reduce_qp(
    const float* __restrict__ P, const float* __restrict__ bq,
    const float* __restrict__ u, const float* __restrict__ v,
    float* __restrict__ qu, float* __restrict__ qv) {
  int idx = blockIdx.x * 256 + threadIdx.x;
  int b = idx >> 8, f4 = idx & 255;
  size_t off = (size_t)b * 1024 + 4 * f4;
  float4 s = *(const float4*)&P[off];
#pragma unroll
  for (int kc = 1; kc < 8; ++kc) {
    float4 t4 = *(const float4*)&P[(size_t)kc * 65536 + off];
    s.x += t4.x; s.y += t4.y; s.z += t4.z; s.w += t4.w;
  }
  float4 bb = *(const float4*)&bq[4 * f4];
  s.x += bb.x; s.y += bb.y; s.z += bb.z; s.w += bb.w;
  float4 uu = *(const float4*)&u[4 * f4];
  float4 vv = *(const float4*)&v[4 * f4];
  float4 o1 = make_float4(s.x + uu.x, s.y + uu.y, s.z + uu.z, s.w + uu.w);
  float4 o2 = make_float4(s.x + vv.x, s.y + vv.y, s.z + vv.z, s.w + vv.w);
  *(float4*)&qu[off] = o1;
  *(float4*)&qv[off] = o2;
}

__global__ __launch_bounds__(256) void k_reduce1(
    const float* __restrict__ P, const float* __restrict__ bias,
    float* __restrict__ out) {
  int idx = blockIdx.x * 256 + threadIdx.x;
  int b = idx >> 8, f4 = idx & 255;
  size_t off = (size_t)b * 1024 + 4 * f4;
  float4 s = *(const float4*)&P[off];
#pragma unroll
  for (int kc = 1; kc < 8; ++kc) {
    float4 t4 = *(const float4*)&P[(size_t)kc * 65536 + off];
    s.x += t4.x; s.y += t4.y; s.z += t4.z; s.w += t4.w;
  }
  float4 bb = *(const float4*)&bias[4 * f4];
  s.x += bb.x; s.y += bb.y; s.z += bb.z; s.w += bb.w;
  *(float4*)&out[off] = s;
}

// ---------------- wtilde: per-h GEMM ----------------
__global__ __launch_bounds__(256) void k_wtilde(
    const float* __restrict__ qu, const float* __restrict__ Wk,
    float* __restrict__ wt) {
  __shared__ __attribute__((aligned(16))) float a_s[64 * 68];
  __shared__ __attribute__((aligned(16))) float w_s[64 * 68];
  int t = threadIdx.x, ct = blockIdx.x, h = blockIdx.y;
  for (int idx = t; idx < 1024; idx += 256) {
    int bb = idx >> 4, f4 = idx & 15;
    *(float4*)&a_s[bb * 68 + 4 * f4] =
        *(const float4*)&qu[(size_t)bb * 1024 + h * 64 + 4 * f4];
  }
  for (int idx = t; idx < 1024; idx += 256) {
    int cc = idx >> 4, f4 = idx & 15;
    *(float4*)&w_s[cc * 68 + 4 * f4] =
        *(const float4*)&Wk[(size_t)(ct * 64 + cc) * 1024 + h * 64 + 4 * f4];
  }
  __syncthreads();
  int c0 = (t & 15) * 4, b0 = (t >> 4) * 4;
  float acc[4][4] = {};
  for (int d = 0; d < 64; d += 4) {
    float4 w0 = *(const float4*)&w_s[(c0 + 0) * 68 + d];
    float4 w1 = *(const float4*)&w_s[(c0 + 1) * 68 + d];
    float4 w2 = *(const float4*)&w_s[(c0 + 2) * 68 + d];
    float4 w3 = *(const float4*)&w_s[(c0 + 3) * 68 + d];
#pragma unroll
    for (int i = 0; i < 4; ++i) {
      float4 av = *(const float4*)&a_s[(b0 + i) * 68 + d];
      acc[i][0] += av.x * w0.x + av.y * w0.y + av.z * w0.z + av.w * w0.w;
      acc[i][1] += av.x * w1.x + av.y * w1.y + av.z * w1.z + av.w * w1.w;
      acc[i][2] += av.x * w2.x + av.y * w2.y + av.z * w2.z + av.w * w2.w;
      acc[i][3] += av.x * w3.x + av.y * w3.y + av.z * w3.z + av.w * w3.w;
    }
  }
#pragma unroll
  for (int i = 0; i < 4; ++i) {
    float4 o = make_float4(acc[i][0], acc[i][1], acc[i][2], acc[i][3]);
    *(float4*)&wt[(size_t)((b0 + i) * 16 + h) * 1024 + ct * 64 + c0] = o;
  }
}

// ---------------- sinusoidal table, reversed ----------------
__global__ void k_rtab(float* __restrict__ rtab) {
  int idx = blockIdx.x * 256 + threadIdx.x;
  if (idx >= LL * 64) return;
  int l = idx >> 6, d = idx & 63;
  float p = (float)(LL - 1 - l);
  int dd = d & 31;
  float f = 1.0f / powf(10000.0f, (float)dd * (1.0f / 32.0f));
  float a = p * f;
  rtab[idx] = (d < 32) ? sinf(a) : cosf(a);
}

// ---------------- bd[b,h,l] = sum_d qv[b,h,d]*rtab[l,d] ----------------
// grid (17, 64): 128 l-rows per block
__global__ __launch_bounds__(256) void k_bd(
    const float* __restrict__ qv, const float* __restrict__ rtab,
    float* __restrict__ bd) {
  __shared__ __attribute__((aligned(16))) float rt_s[128 * 68];
  int t = threadIdx.x, ch = blockIdx.x, b = blockIdx.y;
  int l0 = ch * 128;
  int nrows = min(128, LL - l0);
  for (int idx = t; idx < nrows * 16; idx += 256) {
    int r = idx >> 4, d4 = idx & 15;
    *(float4*)&rt_s[r * 68 + 4 * d4] =
        *(const float4*)&rtab[(size_t)(l0 + r) * 64 + 4 * d4];
  }
  __syncthreads();
  for (int idx = t; idx < 16 * 128; idx += 256) {
    int h = idx >> 7, r = idx & 127;
    if (r < nrows) {
      const float* qh = &qv[(size_t)b * 1024 + h * 64];
      const float* rr = &rt_s[r * 68];
      float s = 0.f;
#pragma unroll
      for (int d4 = 0; d4 < 16; ++d4) {
        float4 rv = *(const float4*)&rr[4 * d4];
        float4 qq = *(const float4*)&qh[4 * d4];
        s += rv.x * qq.x + rv.y * qq.y + rv.z * qq.z + rv.w * qq.w;
      }
      bd[(size_t)(b * 16 + h) * LL + l0 + r] = s;
    }
  }
}

// ---------------- logits via MFMA (bf16x3 hi/lo for fp32-grade precision) -------
// grid (33, 64): 64 rows per block (4 waves x 16 rows), 16 h, K = 1024 c in
// 8 chunks of 128. A = cat rows (M), B = wt (N=16 h). Fragments assumed
// contiguous-K: A: row=lane&15, k=8*(lane>>4)+e; B: col=lane&15, same k.
// C/D (m89-verified): col=lane&15, row=(lane>>4)*4+reg.
// LDS: bf16 hi/lo tiles with 16B-slot XOR swizzle (s^(r&7)).
__global__ __launch_bounds__(256) void k_logits_mfma(
    const float* __restrict__ x, const float* __restrict__ mem,
    const float* __restrict__ wt, const float* __restrict__ bd,
    float* __restrict__ logits) {
  __shared__ short cat_hi[64 * 128];  // [64 r][16 slots][8 bf16] 16 KB
  __shared__ short cat_lo[64 * 128];
  __shared__ short wt_hi[16 * 128];   // [16 h][16 slots][8 bf16] 4 KB
  __shared__ short wt_lo[16 * 128];
  int t = threadIdx.x;
  int lane = t & 63, w = t >> 6;
  int b = blockIdx.y, tile = blockIdx.x;
  int r0 = tile * 64;
  const float* xrow = &x[(size_t)b * 1024];
  const float* memb = &mem[(size_t)b * (size_t)MM * 1024];
  const float* wtb = &wt[(size_t)b * 16384];

  f32x4 acc = {0.f, 0.f, 0.f, 0.f};
  int arow = w * 16 + (lane & 15);      // A row (local)
  int hrow = lane & 15;                 // B col = h
  int sg = lane >> 4;                   // k-slot subgroup

  for (int c0 = 0; c0 < 1024; c0 += 128) {
    if (c0) __syncthreads();
    // stage cat: 64 rows x 128 c fp32 -> bf16 hi/lo (8 passes)
#pragma unroll
    for (int p = 0; p < 8; ++p) {
      int r = (t >> 5) + 8 * p, c4 = t & 31;
      int l = min(r0 + r, LL - 1);
      const float* src = (l < MM) ? &memb[(size_t)l * 1024] : xrow;
      float4 v = *(const float4*)&src[c0 + 4 * c4];
      int s = c4 >> 1, half = c4 & 1;
      int base = (r * 16 + (s ^ (r & 7))) * 8 + half * 4;
      short4v hi, lo;
      hi[0] = f2bf(v.x); lo[0] = f2bf(v.x - bf2f(hi[0]));
      hi[1] = f2bf(v.y); lo[1] = f2bf(v.y - bf2f(hi[1]));
      hi[2] = f2bf(v.z); lo[2] = f2bf(v.z - bf2f(hi[2]));
      hi[3] = f2bf(v.w); lo[3] = f2bf(v.w - bf2f(hi[3]));
      *(short4v*)&cat_hi[base] = hi;
      *(short4v*)&cat_lo[base] = lo;
    }
    // stage wt: 16 h x 128 c (2 passes)
#pragma unroll
    for (int p = 0; p < 2; ++p) {
      int hr = (t >> 5) + 8 * p, c4 = t & 31;
      float4 v = *(const float4*)&wtb[(size_t)hr * 1024 + c0 + 4 * c4];
      int s = c4 >> 1, half = c4 & 1;
      int base = (hr * 16 + (s ^ (hr & 7))) * 8 + half * 4;
      short4v hi, lo;
      hi[0] = f2bf(v.x); lo[0] = f2bf(v.x - bf2f(hi[0]));
      hi[1] = f2bf(v.y); lo[1] = f2bf(v.y - bf2f(hi[1]));
      hi[2] = f2bf(v.z); lo[2] = f2bf(v.z - bf2f(hi[2]));
      hi[3] = f2bf(v.w); lo[3] = f2bf(v.w - bf2f(hi[3]));
      *(short4v*)&wt_hi[base] = hi;
      *(short4v*)&wt_lo[base] = lo;
    }
    __syncthreads();
    // 4 K-steps of 32 c; 3 MFMA each (hi*hi + hi*lo + lo*hi)
#pragma unroll
    for (int kk = 0; kk < 4; ++kk) {
      int scat = 4 * kk + sg;
      int abase = (arow * 16 + (scat ^ (arow & 7))) * 8;
      int bbase = (hrow * 16 + (scat ^ (hrow & 7))) * 8;
      short8v a_hi = *(const short8v*)&cat_hi[abase];
      short8v a_lo = *(const short8v*)&cat_lo[abase];
      short8v b_hi = *(const short8v*)&wt_hi[bbase];
      short8v b_lo = *(const short8v*)&wt_lo[bbase];
      acc = __builtin_amdgcn_mfma_f32_16x16x32_bf16(a_hi, b_hi, acc, 0, 0, 0);
      acc = __builtin_amdgcn_mfma_f32_16x16x32_bf16(a_hi, b_lo, acc, 0, 0, 0);
      acc = __builtin_amdgcn_mfma_f32_16x16x32_bf16(a_lo, b_hi, acc, 0, 0, 0);
    }
  }
  // store: lane holds h = lane&15, rows (lane>>4)*4 + i
#pragma unroll
  for (int i = 0; i < 4; ++i) {
    int row = r0 + w * 16 + sg * 4 + i;
    if (row < LL) {
      size_t o = (size_t)(b * 16 + hrow) * LL + row;
      logits[o] = (acc[i] + bd[o]) * SCALE;
    }
  }
}

// ---------------- softmax over l, in place. grid 1024 (b*16+h) ----------------
__global__ __launch_bounds__(256) void k_softmax(float* __restrict__ logits) {
  __shared__ float red[8];
  int t = threadIdx.x;
  size_t base = (size_t)blockIdx.x * LL;
  float rv[9];
  float m = -1e30f;
#pragma unroll
  for (int k = 0; k < 9; ++k) {
    int i = t + k * 256;
    rv[k] = (i < LL) ? logits[base + i] : -1e30f;
    m = fmaxf(m, rv[k]);
  }
#pragma unroll
  for (int s = 1; s < 64; s <<= 1) m = fmaxf(m, __shfl_xor(m, s, 64));
  if ((t & 63) == 0) red[t >> 6] = m;
  __syncthreads();
  m = fmaxf(fmaxf(red[0], red[1]), fmaxf(red[2], red[3]));
  float sum = 0.f;
#pragma unroll
  for (int k = 0; k < 9; ++k) {
    int i = t + k * 256;
    float e = __expf(rv[k] - m);
    rv[k] = e;
    if (i < LL) sum += e;
  }
#pragma unroll
  for (int s = 1; s < 64; s <<= 1) sum += __shfl_xor(sum, s, 64);
  if ((t & 63) == 0) red[4 + (t >> 6)] = sum;
  __syncthreads();
  float inv = 1.0f / (red[4] + red[5] + red[6] + red[7]);
#pragma unroll
  for (int k = 0; k < 9; ++k) {
    int i = t + k * 256;
    if (i < LL) logits[base + i] = rv[k] * inv;
  }
}

// ---------------- ctx pass: register-resident, global-direct ----------------
__global__ __launch_bounds__(256) void k_ctx(
    const float* __restrict__ x, const float* __restrict__ mem,
    const float* __restrict__ attn, float* __restrict__ part) {
  __shared__ __attribute__((aligned(16))) float att_s[CHC * 20];
  int t = threadIdx.x;
  int lane = t & 63, w = t >> 6;
  int b = blockIdx.y;
  int ch = blockIdx.x >> 2, cq = blockIdx.x & 3;
  int l0 = ch * CHC, lend = min(LL, l0 + CHC);
  int natt = lend - l0;
  int c_off = cq * 256 + lane * 4;
#pragma unroll
  for (int h = 0; h < 16; ++h)
    for (int r = t; r < natt; r += 256)
      att_s[r * 20 + h] = attn[(size_t)(b * 16 + h) * LL + l0 + r];
  __syncthreads();
  float4 acc[16];
#pragma unroll
  for (int i = 0; i < 16; ++i) acc[i] = make_float4(0.f, 0.f, 0.f, 0.f);
  const float* xrow = &x[(size_t)b * 1024 + c_off];
  const float* memb = &mem[(size_t)b * MM * 1024 + c_off];

  for (int g0 = l0 + w * 8; g0 < lend; g0 += 32) {
    int nr = min(8, lend - g0);
    float4 rb[8];
#pragma unroll
    for (int r = 0; r < 8; ++r) {
      int l = g0 + r;
      rb[r] = *(const float4*)((l < MM) ? &memb[(size_t)l * 1024] : xrow);
    }
#pragma unroll
    for (int r = 0; r < 8; ++r) {
      if (r < nr) {
        int ri = g0 + r - l0;
        const float4* a4 = (const float4*)&att_s[ri * 20];
        float4 aA = a4[0], aB = a4[1], aC = a4[2], aD = a4[3];
        float4 rv = rb[r];
#define ACC1(i, s)                                                       \
  acc[i].x += (s) * rv.x; acc[i].y += (s) * rv.y;                        \
  acc[i].z += (s) * rv.z; acc[i].w += (s) * rv.w;
        ACC1(0, aA.x) ACC1(1, aA.y) ACC1(2, aA.z) ACC1(3, aA.w)
        ACC1(4, aB.x) ACC1(5, aB.y) ACC1(6, aB.z) ACC1(7, aB.w)
        ACC1(8, aC.x) ACC1(9, aC.y) ACC1(10, aC.z) ACC1(11, aC.w)
        ACC1(12, aD.x) ACC1(13, aD.y) ACC1(14, aD.z) ACC1(15, aD.w)
#undef ACC1
      }
    }
  }
  __syncthreads();
  float* accb = att_s;
  for (int ww = 0; ww < 4; ++ww) {
    if (w == ww) {
      if (ww == 0) {
#pragma unroll
        for (int h = 0; h < 16; ++h)
          *(float4*)&accb[h * 256 + lane * 4] = acc[h];
      } else {
#pragma unroll
        for (int h = 0; h < 16; ++h) {
          float4 vv = *(const float4*)&accb[h * 256 + lane * 4];
          vv.x += acc[h].x; vv.y += acc[h].y;
          vv.z += acc[h].z; vv.w += acc[h].w;
          *(float4*)&accb[h * 256 + lane * 4] = vv;
        }
      }
    }
    __syncthreads();
  }
  size_t pb = (size_t)((b * NCHC + ch) * 16) * 1024 + cq * 256;
  for (int idx = t; idx < 1024; idx += 256) {
    int h = idx >> 6, c4 = idx & 63;
    *(float4*)&part[pb + (size_t)h * 1024 + 4 * c4] =
        *(const float4*)&accb[h * 256 + 4 * c4];
  }
}

// ---------------- sum 9 chunk partials -> ctx ----------------
__global__ __launch_bounds__(256) void k_ctxreduce(
    const float* __restrict__ part, float* __restrict__ ctx) {
  int o4 = blockIdx.x * 256 + threadIdx.x;
  size_t o = (size_t)o4 * 4;
  int b = (int)(o >> 14);
  int rem = (int)(o & 16383);
  const float* p = &part[(size_t)b * (NCHC * 16384) + rem];
  float4 s = *(const float4*)p;
#pragma unroll
  for (int chk = 1; chk < NCHC; ++chk) {
    float4 v = *(const float4*)&p[(size_t)chk * 16384];
    s.x += v.x; s.y += v.y; s.z += v.z; s.w += v.w;
  }
  *(float4*)&ctx[o] = s;
}

extern "C" void kernel_launch(void* const* d_in, const int* in_sizes, int n_in,
                              void* d_out, int out_size, void* d_ws,
                              size_t ws_size, hipStream_t stream) {
  const float* x = (const float*)d_in[0];
  const float* mem = (const float*)d_in[1];
  const float* Wq = (const float*)d_in[2];
  const float* bq = (const float*)d_in[3];
  const float* Wk = (const float*)d_in[4];
  // d_in[5] = bk : constant over l -> cancels in softmax, unused.
  const float* Wv = (const float*)d_in[6];
  const float* bv = (const float*)d_in[7];
  const float* u_bias = (const float*)d_in[8];
  const float* v_bias = (const float*)d_in[9];
  const float* Wo = (const float*)d_in[10];
  const float* bo = (const float*)d_in[11];
  float* out = (float*)d_out;

  float* ws = (float*)d_ws;
  float* qu = ws;                          // 65,536
  float* qv = qu + 65536;                  // 65,536
  float* wt = qv + 65536;                  // 1,048,576
  float* rtab = wt + 1048576;              // 131,200
  float* bd = rtab + 131200;               // 2,098,176
  float* logits = bd + 2098176;            // 2,098,176
  float* P = logits + 2098176;             // 524,288
  float* ctx = P + 524288;                 // 1,048,576
  float* out1 = ctx + 1048576;             // 65,536
  float* part = out1 + 65536;              // 9,437,184

  k_gemm<<<dim3(16, 8), 256, 0, stream>>>(x, 1024, 0, Wq, P);
  k_rtab<<<dim3(513), 256, 0, stream>>>(rtab);
  k_reduce_qp<<<dim3(64), 256, 0, stream>>>(P, bq, u_bias, v_bias, qu, qv);
  k_wtilde<<<dim3(16, 16), 256, 0, stream>>>(qu, Wk, wt);
  k_bd<<<dim3(17, 64), 256, 0, stream>>>(qv, rtab, bd);
  k_logits_mfma<<<dim3(33, 64), 256, 0, stream>>>(x, mem, wt, bd, logits);
  k_softmax<<<dim3(1024), 256, 0, stream>>>(logits);
  k_ctx<<<dim3(36, 64), 256, 0, stream>>>(x, mem, logits, part);
  k_ctxreduce<<<dim3(1024), 256, 0, stream>>>(part, ctx);
  k_gemm<<<dim3(16, 8), 256, 0, stream>>>(ctx, 16384, 1024, Wv, P);
  k_reduce1<<<dim3(64), 256, 0, stream>>>(P, bv, out1);
  k_gemm<<<dim3(16, 8), 256, 0, stream>>>(out1, 1024, 0, Wo, P);
  k_reduce1<<<dim3(64), 256, 0, stream>>>(P, bo, out);
}

// Round 16
// 354.940 us; speedup vs baseline: 1.0160x; 1.0160x over previous
//
#include <hip/hip_runtime.h>
#include <hip/hip_bf16.h>
#include <math.h>

// Problem constants
#define B   64
#define C   1024
#define HH  16
#define DD  64
#define MM  2048
#define LL  2049   // M+1
#define SCALE 0.125f
#define NCHC 9     // ctx row chunks
#define CHC  228   // rows per ctx chunk (9*228 = 2052 >= 2049)
#define LCH  16    // logits chunks (16*129 = 2064 >= 2049), grid 1024 = 4/CU exact
#define LCHR 129   // rows per logits chunk

// DPP helper: keep + dpp<CTRL>(send). 0xB1 = quad_perm xor1, 0x4E = quad_perm
// xor2, 0x128 = row_ror:8 (== lane^8 within each 16-lane row).
template <int CTRL>
__device__ __forceinline__ float dpp_add(float keep, float send) {
  int moved =
      __builtin_amdgcn_update_dpp(0, __float_as_int(send), CTRL, 0xF, 0xF, true);
  return keep + __int_as_float(moved);
}

// ---------------- generic split-K GEMM: out_partial[kc][64][1024] ----------------
__global__ __launch_bounds__(256) void k_gemm(
    const float* __restrict__ A, int a_row_stride, int a_bx_off,
    const float* __restrict__ W, float* __restrict__ P) {
  __shared__ __attribute__((aligned(16))) float a_s[64 * 132];
  __shared__ __attribute__((aligned(16))) float b_s[128 * 68];
  int t = threadIdx.x;
  int jt = blockIdx.x, kc = blockIdx.y;
  const float* Ab = A + (size_t)jt * a_bx_off;
  int k0 = kc * 128;
  for (int idx = t; idx < 2048; idx += 256) {
    int bb = idx >> 5, f4 = idx & 31;
    float4 v = *(const float4*)&Ab[(size_t)bb * a_row_stride + k0 + 4 * f4];
    *(float4*)&a_s[bb * 132 + 4 * f4] = v;
  }
  for (int idx = t; idx < 2048; idx += 256) {
    int kk = idx >> 4, f4 = idx & 15;
    float4 v = *(const float4*)&W[(size_t)(k0 + kk) * 1024 + jt * 64 + 4 * f4];
    *(float4*)&b_s[kk * 68 + 4 * f4] = v;
  }
  __syncthreads();
  int j0 = (t & 15) * 4, b0 = (t >> 4) * 4;
  float4 acc[4];
#pragma unroll
  for (int i = 0; i < 4; ++i) acc[i] = make_float4(0.f, 0.f, 0.f, 0.f);
  for (int k = 0; k < 128; k += 4) {
    float4 w0 = *(const float4*)&b_s[(k + 0) * 68 + j0];
    float4 w1 = *(const float4*)&b_s[(k + 1) * 68 + j0];
    float4 w2 = *(const float4*)&b_s[(k + 2) * 68 + j0];
    float4 w3 = *(const float4*)&b_s[(k + 3) * 68 + j0];
#pragma unroll
    for (int i = 0; i < 4; ++i) {
      float4 av = *(const float4*)&a_s[(b0 + i) * 132 + k];
      acc[i].x += av.x * w0.x + av.y * w1.x + av.z * w2.x + av.w * w3.x;
      acc[i].y += av.x * w0.y + av.y * w1.y + av.z * w2.y + av.w * w3.y;
      acc[i].z += av.x * w0.z + av.y * w1.z + av.z * w2.z + av.w * w3.z;
      acc[i].w += av.x * w0.w + av.y * w1.w + av.z * w2.w + av.w * w3.w;
    }
  }
  size_t ob = (size_t)kc * 65536 + jt * 64;
#pragma unroll
  for (int i = 0; i < 4; ++i)
    *(float4*)&P[ob + (size_t)(b0 + i) * 1024 + j0] = acc[i];
}

// ---------------- split-K GEMM with 9-chunk part-sum A staging (Wv path) --------
// A[bb][k] = sum_ch part[((bb*9+ch)*16 + jt)*1024 + k]; replaces ctxreduce+gemm.
__global__ __launch_bounds__(256) void k_gemm_acc(
    const float* __restrict__ part, const float* __restrict__ W,
    float* __restrict__ P) {
  __shared__ __attribute__((aligned(16))) float a_s[64 * 132];
  __shared__ __attribute__((aligned(16))) float b_s[128 * 68];
  int t = threadIdx.x;
  int jt = blockIdx.x, kc = blockIdx.y;
  int k0 = kc * 128;
  for (int idx = t; idx < 2048; idx += 256) {
    int bb = idx >> 5, f4 = idx & 31;
    const float* pb =
        &part[((size_t)(bb * NCHC) * 16 + jt) * 1024 + k0 + 4 * f4];
    float4 v = *(const float4*)pb;
#pragma unroll
    for (int chk = 1; chk < NCHC; ++chk) {
      float4 u = *(const float4*)&pb[(size_t)chk * 16384];
      v.x += u.x; v.y += u.y; v.z += u.z; v.w += u.w;
    }
    *(float4*)&a_s[bb * 132 + 4 * f4] = v;
  }
  for (int idx = t; idx < 2048; idx += 256) {
    int kk = idx >> 4, f4 = idx & 15;
    float4 v = *(const float4*)&W[(size_t)(k0 + kk) * 1024 + jt * 64 + 4 * f4];
    *(float4*)&b_s[kk * 68 + 4 * f4] = v;
  }
  __syncthreads();
  int j0 = (t & 15) * 4, b0 = (t >> 4) * 4;
  float4 acc[4];
#pragma unroll
  for (int i = 0; i < 4; ++i) acc[i] = make_float4(0.f, 0.f, 0.f, 0.f);
  for (int k = 0; k < 128; k += 4) {
    float4 w0 = *(const float4*)&b_s[(k + 0) * 68 + j0];
    float4 w1 = *(const float4*)&b_s[(k + 1) * 68 + j0];
    float4 w2 = *(const float4*)&b_s[(k + 2) * 68 + j0];
    float4 w3 = *(const float4*)&b_s[(k + 3) * 68 + j0];
#pragma unroll
    for (int i = 0; i < 4; ++i) {
      float4 av = *(const float4*)&a_s[(b0 + i) * 132 + k];
      acc[i].x += av.x * w0.x + av.y * w1.x + av.z * w2.x + av.w * w3.x;
      acc[i].y += av.x * w0.y + av.y * w1.y + av.z * w2.y + av.w * w3.y;
      acc[i].z += av.x * w0.z + av.y * w1.z + av.z * w2.z + av.w * w3.z;
      acc[i].w += av.x * w0.w + av.y * w1.w + av.z * w2.w + av.w * w3.w;
    }
  }
  size_t ob = (size_t)kc * 65536 + jt * 64;
#pragma unroll
  for (int i = 0; i < 4; ++i)
    *(float4*)&P[ob + (size_t)(b0 + i) * 1024 + j0] = acc[i];
}

__global__ __launch_bounds__(256) void k_reduce_qp(
    const float* __restrict__ P, const float* __restrict__ bq,
    const float* __restrict__ u, const float* __restrict__ v,
    float* __restrict__ qu, float* __restrict__ qv) {
  int idx = blockIdx.x * 256 + threadIdx.x;
  int b = idx >> 8, f4 = idx & 255;
  size_t off = (size_t)b * 1024 + 4 * f4;
  float4 s = *(const float4*)&P[off];
#pragma unroll
  for (int kc = 1; kc < 8; ++kc) {
    float4 t4 = *(const float4*)&P[(size_t)kc * 65536 + off];
    s.x += t4.x; s.y += t4.y; s.z += t4.z; s.w += t4.w;
  }
  float4 bb = *(const float4*)&bq[4 * f4];
  s.x += bb.x; s.y += bb.y; s.z += bb.z; s.w += bb.w;
  float4 uu = *(const float4*)&u[4 * f4];
  float4 vv = *(const float4*)&v[4 * f4];
  float4 o1 = make_float4(s.x + uu.x, s.y + uu.y, s.z + uu.z, s.w + uu.w);
  float4 o2 = make_float4(s.x + vv.x, s.y + vv.y, s.z + vv.z, s.w + vv.w);
  *(float4*)&qu[off] = o1;
  *(float4*)&qv[off] = o2;
}

__global__ __launch_bounds__(256) void k_reduce1(
    const float* __restrict__ P, const float* __restrict__ bias,
    float* __restrict__ out) {
  int idx = blockIdx.x * 256 + threadIdx.x;
  int b = idx >> 8, f4 = idx & 255;
  size_t off = (size_t)b * 1024 + 4 * f4;
  float4 s = *(const float4*)&P[off];
#pragma unroll
  for (int kc = 1; kc < 8; ++kc) {
    float4 t4 = *(const float4*)&P[(size_t)kc * 65536 + off];
    s.x += t4.x; s.y += t4.y; s.z += t4.z; s.w += t4.w;
  }
  float4 bb = *(const float4*)&bias[4 * f4];
  s.x += bb.x; s.y += bb.y; s.z += bb.z; s.w += bb.w;
  *(float4*)&out[off] = s;
}

// ---------------- wtilde: per-h GEMM ----------------
__global__ __launch_bounds__(256) void k_wtilde(
    const float* __restrict__ qu, const float* __restrict__ Wk,
    float* __restrict__ wt) {
  __shared__ __attribute__((aligned(16))) float a_s[64 * 68];
  __shared__ __attribute__((aligned(16))) float w_s[64 * 68];
  int t = threadIdx.x, ct = blockIdx.x, h = blockIdx.y;
  for (int idx = t; idx < 1024; idx += 256) {
    int bb = idx >> 4, f4 = idx & 15;
    *(float4*)&a_s[bb * 68 + 4 * f4] =
        *(const float4*)&qu[(size_t)bb * 1024 + h * 64 + 4 * f4];
  }
  for (int idx = t; idx < 1024; idx += 256) {
    int cc = idx >> 4, f4 = idx & 15;
    *(float4*)&w_s[cc * 68 + 4 * f4] =
        *(const float4*)&Wk[(size_t)(ct * 64 + cc) * 1024 + h * 64 + 4 * f4];
  }
  __syncthreads();
  int c0 = (t & 15) * 4, b0 = (t >> 4) * 4;
  float acc[4][4] = {};
  for (int d = 0; d < 64; d += 4) {
    float4 w0 = *(const float4*)&w_s[(c0 + 0) * 68 + d];
    float4 w1 = *(const float4*)&w_s[(c0 + 1) * 68 + d];
    float4 w2 = *(const float4*)&w_s[(c0 + 2) * 68 + d];
    float4 w3 = *(const float4*)&w_s[(c0 + 3) * 68 + d];
#pragma unroll
    for (int i = 0; i < 4; ++i) {
      float4 av = *(const float4*)&a_s[(b0 + i) * 68 + d];
      acc[i][0] += av.x * w0.x + av.y * w0.y + av.z * w0.z + av.w * w0.w;
      acc[i][1] += av.x * w1.x + av.y * w1.y + av.z * w1.z + av.w * w1.w;
      acc[i][2] += av.x * w2.x + av.y * w2.y + av.z * w2.z + av.w * w2.w;
      acc[i][3] += av.x * w3.x + av.y * w3.y + av.z * w3.z + av.w * w3.w;
    }
  }
#pragma unroll
  for (int i = 0; i < 4; ++i) {
    float4 o = make_float4(acc[i][0], acc[i][1], acc[i][2], acc[i][3]);
    *(float4*)&wt[(size_t)((b0 + i) * 16 + h) * 1024 + ct * 64 + c0] = o;
  }
}

// ---------------- sinusoidal table, reversed ----------------
__global__ void k_rtab(float* __restrict__ rtab) {
  int idx = blockIdx.x * 256 + threadIdx.x;
  if (idx >= LL * 64) return;
  int l = idx >> 6, d = idx & 63;
  float p = (float)(LL - 1 - l);
  int dd = d & 31;
  float f = 1.0f / powf(10000.0f, (float)dd * (1.0f / 32.0f));
  float a = p * f;
  rtab[idx] = (d < 32) ? sinf(a) : cosf(a);
}

// ---------------- bd[b,h,l] = sum_d qv[b,h,d]*rtab[l,d] ----------------
// grid (17, 64): 128 l-rows per block
__global__ __launch_bounds__(256) void k_bd(
    const float* __restrict__ qv, const float* __restrict__ rtab,
    float* __restrict__ bd) {
  __shared__ __attribute__((aligned(16))) float rt_s[128 * 68];
  int t = threadIdx.x, ch = blockIdx.x, b = blockIdx.y;
  int l0 = ch * 128;
  int nrows = min(128, LL - l0);
  for (int idx = t; idx < nrows * 16; idx += 256) {
    int r = idx >> 4, d4 = idx & 15;
    *(float4*)&rt_s[r * 68 + 4 * d4] =
        *(const float4*)&rtab[(size_t)(l0 + r) * 64 + 4 * d4];
  }
  __syncthreads();
  for (int idx = t; idx < 16 * 128; idx += 256) {
    int h = idx >> 7, r = idx & 127;
    if (r < nrows) {
      const float* qh = &qv[(size_t)b * 1024 + h * 64];
      const float* rr = &rt_s[r * 68];
      float s = 0.f;
#pragma unroll
      for (int d4 = 0; d4 < 16; ++d4) {
        float4 rv = *(const float4*)&rr[4 * d4];
        float4 qq = *(const float4*)&qh[4 * d4];
        s += rv.x * qq.x + rv.y * qq.y + rv.z * qq.z + rv.w * qq.w;
      }
      bd[(size_t)(b * 16 + h) * LL + l0 + r] = s;
    }
  }
}

// ---------------- logits pass + per-chunk (m, sumexp) stats ----------------
// Hot loop byte-identical to R14 (DPP butterfly, barrier-free, ping-pong).
// Epilogue: 16-lane groups (h = t>>4, sub = t&15) compute lo, store raw
// logits, and reduce per-chunk max / sum-exp -> ms (softmax kernel deleted).
__global__ __launch_bounds__(256, 4) void k_logits(
    const float* __restrict__ x, const float* __restrict__ mem,
    const float* __restrict__ wt, const float* __restrict__ bd,
    float* __restrict__ logits, float* __restrict__ ms) {
  __shared__ float red_s[LCHR * 68];  // 35,088 B
  int t = threadIdx.x;
  int lane = t & 63, w = t >> 6;
  int b = blockIdx.y, ch = blockIdx.x;
  int l0 = ch * LCHR, lend = min(LL, l0 + LCHR);
  int c_off = w * 256 + lane * 4;
  float4 wr[16];
#pragma unroll
  for (int h = 0; h < 16; ++h)
    wr[h] = *(const float4*)&wt[(size_t)(b * 16 + h) * 1024 + c_off];
  const float* xrow = &x[(size_t)b * 1024 + c_off];
  const float* memb = &mem[(size_t)b * MM * 1024 + c_off];
  bool u0 = (lane & 1) != 0, u1 = (lane & 2) != 0;
  bool u2 = (lane & 4) != 0, u3 = (lane & 8) != 0;
  int hmap = ((lane & 1) << 3) | ((lane & 2) << 1) | ((lane & 4) >> 1) |
             ((lane & 8) >> 3);

#define LOADROWS(dst, base)                                                  \
  {                                                                          \
    _Pragma("unroll") for (int r = 0; r < 4; ++r) {                          \
      int l = min((base) + r, LL - 1);                                       \
      dst[r] = *(const float4*)((l < MM) ? &memb[(size_t)l * 1024] : xrow);  \
    }                                                                        \
  }
#define COMPROWS(src, base)                                                  \
  {                                                                          \
    _Pragma("unroll") for (int r = 0; r < 4; ++r) {                          \
      int row = (base) + r;                                                  \
      if (row < lend) {                                                      \
        float4 rv = src[r];                                                  \
        float p[16];                                                         \
        _Pragma("unroll") for (int h = 0; h < 16; ++h)                       \
            p[h] = rv.x * wr[h].x + rv.y * wr[h].y + rv.z * wr[h].z +        \
                   rv.w * wr[h].w;                                           \
        _Pragma("unroll") for (int i = 0; i < 8; ++i) {                      \
          float send = u0 ? p[i] : p[i + 8];                                 \
          float keep = u0 ? p[i + 8] : p[i];                                 \
          p[i] = dpp_add<0xB1>(keep, send);                                  \
        }                                                                    \
        _Pragma("unroll") for (int i = 0; i < 4; ++i) {                      \
          float send = u1 ? p[i] : p[i + 4];                                 \
          float keep = u1 ? p[i + 4] : p[i];                                 \
          p[i] = dpp_add<0x4E>(keep, send);                                  \
        }                                                                    \
        _Pragma("unroll") for (int i = 0; i < 2; ++i) {                      \
          float send = u2 ? p[i] : p[i + 2];                                 \
          float keep = u2 ? p[i + 2] : p[i];                                 \
          p[i] = keep + __shfl_xor(send, 4, 64);                             \
        }                                                                    \
        {                                                                    \
          float send = u3 ? p[0] : p[1];                                     \
          float keep = u3 ? p[1] : p[0];                                     \
          float u = dpp_add<0x128>(keep, send);                              \
          u += __shfl_xor(u, 16, 64);                                        \
          u += __shfl_xor(u, 32, 64);                                        \
          if (lane < 16) red_s[(row - l0) * 68 + w * 16 + hmap] = u;         \
        }                                                                    \
      }                                                                      \
    }                                                                        \
  }

  float4 rbA[4], rbB[4];
  LOADROWS(rbA, l0)
  for (int g0 = l0; g0 < lend; g0 += 8) {
    LOADROWS(rbB, g0 + 4)
    COMPROWS(rbA, g0)
    if (g0 + 8 < lend) LOADROWS(rbA, g0 + 8)
    COMPROWS(rbB, g0 + 4)
  }
#undef LOADROWS
#undef COMPROWS

  __syncthreads();  // single barrier
  // epilogue: h = t>>4, sub = t&15; rows sub, sub+16, ... (static lov idx)
  int nrows = lend - l0;
  int h = t >> 4, sub = t & 15;
  float lov[9];
  float m = -3e38f;
#pragma unroll
  for (int i = 0; i < 9; ++i) {
    int r = sub + 16 * i;
    float lo = -3e38f;
    if (r < nrows) {
      float s4 = red_s[r * 68 + h] + red_s[r * 68 + 16 + h] +
                 red_s[r * 68 + 32 + h] + red_s[r * 68 + 48 + h];
      size_t o = (size_t)(b * 16 + h) * LL + l0 + r;
      lo = (s4 + bd[o]) * SCALE;
      logits[o] = lo;
    }
    lov[i] = lo;
    m = fmaxf(m, lo);
  }
  // 16-lane group max (groups are 16-aligned within the wave)
  m = fmaxf(m, __shfl_xor(m, 1, 64));
  m = fmaxf(m, __shfl_xor(m, 2, 64));
  m = fmaxf(m, __shfl_xor(m, 4, 64));
  m = fmaxf(m, __shfl_xor(m, 8, 64));
  float ssum = 0.f;
#pragma unroll
  for (int i = 0; i < 9; ++i) ssum += __expf(lov[i] - m);
  ssum += __shfl_xor(ssum, 1, 64);
  ssum += __shfl_xor(ssum, 2, 64);
  ssum += __shfl_xor(ssum, 4, 64);
  ssum += __shfl_xor(ssum, 8, 64);
  if (sub == 0) {
    size_t mo = ((size_t)b * LCH + ch) * 32 + h * 2;
    ms[mo] = m;
    ms[mo + 1] = ssum;
  }
}

// ---------------- ctx pass: softmax applied on the fly (R11-proven preamble) ----
// grid (36, 64): bx = ch*4 + cq. Preamble combines 16 chunk-stats -> (m, 1/den)
// per h; staging reads raw logits and applies exp()*inv.
__global__ __launch_bounds__(256) void k_ctx(
    const float* __restrict__ x, const float* __restrict__ mem,
    const float* __restrict__ logits, const float* __restrict__ ms,
    float* __restrict__ part) {
  __shared__ __attribute__((aligned(16))) float att_s[CHC * 20];
  __shared__ float m_l[16], inv_l[16];
  int t = threadIdx.x;
  int lane = t & 63, w = t >> 6;
  int b = blockIdx.y;
  int ch = blockIdx.x >> 2, cq = blockIdx.x & 3;
  int l0 = ch * CHC, lend = min(LL, l0 + CHC);
  int natt = lend - l0;
  int c_off = cq * 256 + lane * 4;
  if (t < 16) {
    float M = -3e38f;
#pragma unroll
    for (int cc = 0; cc < LCH; ++cc)
      M = fmaxf(M, ms[((size_t)b * LCH + cc) * 32 + t * 2]);
    float den = 0.f;
#pragma unroll
    for (int cc = 0; cc < LCH; ++cc)
      den += __expf(ms[((size_t)b * LCH + cc) * 32 + t * 2] - M) *
             ms[((size_t)b * LCH + cc) * 32 + t * 2 + 1];
    m_l[t] = M;
    inv_l[t] = 1.0f / den;
  }
  __syncthreads();
#pragma unroll
  for (int h = 0; h < 16; ++h)
    for (int r = t; r < natt; r += 256) {
      float lo = logits[(size_t)(b * 16 + h) * LL + l0 + r];
      att_s[r * 20 + h] = __expf(lo - m_l[h]) * inv_l[h];
    }
  __syncthreads();
  float4 acc[16];
#pragma unroll
  for (int i = 0; i < 16; ++i) acc[i] = make_float4(0.f, 0.f, 0.f, 0.f);
  const float* xrow = &x[(size_t)b * 1024 + c_off];
  const float* memb = &mem[(size_t)b * MM * 1024 + c_off];

  for (int g0 = l0 + w * 8; g0 < lend; g0 += 32) {
    int nr = min(8, lend - g0);
    float4 rb[8];
#pragma unroll
    for (int r = 0; r < 8; ++r) {
      int l = g0 + r;
      rb[r] = *(const float4*)((l < MM) ? &memb[(size_t)l * 1024] : xrow);
    }
#pragma unroll
    for (int r = 0; r < 8; ++r) {
      if (r < nr) {
        int ri = g0 + r - l0;
        const float4* a4 = (const float4*)&att_s[ri * 20];
        float4 aA = a4[0], aB = a4[1], aC = a4[2], aD = a4[3];
        float4 rv = rb[r];
#define ACC1(i, s)                                                       \
  acc[i].x += (s) * rv.x; acc[i].y += (s) * rv.y;                        \
  acc[i].z += (s) * rv.z; acc[i].w += (s) * rv.w;
        ACC1(0, aA.x) ACC1(1, aA.y) ACC1(2, aA.z) ACC1(3, aA.w)
        ACC1(4, aB.x) ACC1(5, aB.y) ACC1(6, aB.z) ACC1(7, aB.w)
        ACC1(8, aC.x) ACC1(9, aC.y) ACC1(10, aC.z) ACC1(11, aC.w)
        ACC1(12, aD.x) ACC1(13, aD.y) ACC1(14, aD.z) ACC1(15, aD.w)
#undef ACC1
      }
    }
  }
  // cross-wave merge in LDS (reuse att_s: 4096 <= 4560 floats)
  __syncthreads();
  float* accb = att_s;
  for (int ww = 0; ww < 4; ++ww) {
    if (w == ww) {
      if (ww == 0) {
#pragma unroll
        for (int h = 0; h < 16; ++h)
          *(float4*)&accb[h * 256 + lane * 4] = acc[h];
      } else {
#pragma unroll
        for (int h = 0; h < 16; ++h) {
          float4 vv = *(const float4*)&accb[h * 256 + lane * 4];
          vv.x += acc[h].x; vv.y += acc[h].y;
          vv.z += acc[h].z; vv.w += acc[h].w;
          *(float4*)&accb[h * 256 + lane * 4] = vv;
        }
      }
    }
    __syncthreads();
  }
  size_t pb = (size_t)((b * NCHC + ch) * 16) * 1024 + cq * 256;
  for (int idx = t; idx < 1024; idx += 256) {
    int h = idx >> 6, c4 = idx & 63;
    *(float4*)&part[pb + (size_t)h * 1024 + 4 * c4] =
        *(const float4*)&accb[h * 256 + 4 * c4];
  }
}

extern "C" void kernel_launch(void* const* d_in, const int* in_sizes, int n_in,
                              void* d_out, int out_size, void* d_ws,
                              size_t ws_size, hipStream_t stream) {
  const float* x = (const float*)d_in[0];
  const float* mem = (const float*)d_in[1];
  const float* Wq = (const float*)d_in[2];
  const float* bq = (const float*)d_in[3];
  const float* Wk = (const float*)d_in[4];
  // d_in[5] = bk : constant over l -> cancels in softmax, unused.
  const float* Wv = (const float*)d_in[6];
  const float* bv = (const float*)d_in[7];
  const float* u_bias = (const float*)d_in[8];
  const float* v_bias = (const float*)d_in[9];
  const float* Wo = (const float*)d_in[10];
  const float* bo = (const float*)d_in[11];
  float* out = (float*)d_out;

  float* ws = (float*)d_ws;
  float* qu = ws;                          // 65,536
  float* qv = qu + 65536;                  // 65,536
  float* wt = qv + 65536;                  // 1,048,576
  float* rtab = wt + 1048576;              // 131,200
  float* bd = rtab + 131200;               // 2,098,176
  float* logits = bd + 2098176;            // 2,098,176
  float* ms = logits + 2098176;            // 32,768 (B*LCH*32)
  float* P = ms + 32768;                   // 524,288
  float* out1 = P + 524288;                // 65,536
  float* part = out1 + 65536;              // 9,437,184
  // total ~15.6M floats ~ 62 MB

  k_gemm<<<dim3(16, 8), 256, 0, stream>>>(x, 1024, 0, Wq, P);
  k_rtab<<<dim3(513), 256, 0, stream>>>(rtab);
  k_reduce_qp<<<dim3(64), 256, 0, stream>>>(P, bq, u_bias, v_bias, qu, qv);
  k_wtilde<<<dim3(16, 16), 256, 0, stream>>>(qu, Wk, wt);
  k_bd<<<dim3(17, 64), 256, 0, stream>>>(qv, rtab, bd);
  k_logits<<<dim3(LCH, 64), 256, 0, stream>>>(x, mem, wt, bd, logits, ms);
  k_ctx<<<dim3(36, 64), 256, 0, stream>>>(x, mem, logits, ms, part);
  k_gemm_acc<<<dim3(16, 8), 256, 0, stream>>>(part, Wv, P);
  k_reduce1<<<dim3(64), 256, 0, stream>>>(P, bv, out1);
  k_gemm<<<dim3(16, 8), 256, 0, stream>>>(out1, 1024, 0, Wo, P);
  k_reduce1<<<dim3(64), 256, 0, stream>>>(P, bo, out);
}